// Round 2
// baseline (552.669 us; speedup 1.0000x reference)
//
#include <hip/hip_runtime.h>
#include <hip/hip_bf16.h>

// Dims
#define V_DIM 8192
#define E_DIM 8192
#define KD    512   // K*D = 64*8  (inner dim of GEMM1; also x row length)
#define CO    512   // C*O = 64*8  (output inner dim)

typedef __attribute__((ext_vector_type(8))) short short8;
typedef __attribute__((ext_vector_type(8))) unsigned short ushort8;
typedef __attribute__((ext_vector_type(4))) float f32x4;

__device__ __forceinline__ unsigned short f2b(float f) {
  __hip_bfloat16 h = __float2bfloat16(f);
  return __builtin_bit_cast(unsigned short, h);
}

__device__ __forceinline__ void gload_lds16(const void* g, void* l) {
  __builtin_amdgcn_global_load_lds(
      (const __attribute__((address_space(1))) void*)g,
      (__attribute__((address_space(3))) void*)l, 16, 0, 0);
}

// x (fp32, [V][KD]) -> xb (bf16 bits, same layout)
__global__ void convert_x(const float* __restrict__ x, unsigned short* __restrict__ xb) {
  const size_t i = ((size_t)blockIdx.x * 256 + threadIdx.x) * 8;
  float4 f0 = *(const float4*)(x + i);
  float4 f1 = *(const float4*)(x + i + 4);
  ushort8 u;
  u[0]=f2b(f0.x); u[1]=f2b(f0.y); u[2]=f2b(f0.z); u[3]=f2b(f0.w);
  u[4]=f2b(f1.x); u[5]=f2b(f1.y); u[6]=f2b(f1.z); u[7]=f2b(f1.w);
  *(ushort8*)(xb + i) = u;
}

// Wt[j=c*8+o][kd=k*8+d] = W[o,d,k,c]  (fp32, 512x512); bsum[j] = sum_d b[o,c,d]
__global__ void repack_w(const float* __restrict__ W, const float* __restrict__ b,
                         float* __restrict__ Wt, float* __restrict__ bsum) {
  const int idx = blockIdx.x * 256 + threadIdx.x;  // 0..262143
  const int j = idx >> 9, kd = idx & 511;
  const int c = j >> 3, o = j & 7, k = kd >> 3, d = kd & 7;
  Wt[idx] = W[(((o * 8 + d) * 64 + k) << 6) + c];
  if (idx < 512) {
    const int cc = idx >> 3, oo = idx & 7;
    float s = 0.f;
#pragma unroll
    for (int dd = 0; dd < 8; ++dd) s += b[((oo * 64 + cc) << 3) + dd];
    bsum[idx] = s;
  }
}

// C[m][n] = sum_k A[m][k] * B[n][k]   (A fp32 converted on the fly, B bf16 bits)
// Tile 128x128, BK=64, 512 threads = 8 waves in 2(M) x 4(N); wave tile 64x32.
// LDS chunk swizzle: 16B chunk index ^= (row & 7), applied on both write and read.
template<bool OUT_BF16, bool HASBIAS>
__global__ __launch_bounds__(512)
void gemm_bt(const float* __restrict__ A, const unsigned short* __restrict__ B,
             const float* __restrict__ bias, void* __restrict__ Cout,
             int ldA, int ldB, int ldC, int kdim) {
  __shared__ __align__(16) unsigned short As[2][128 * 64];
  __shared__ __align__(16) unsigned short Bs[2][128 * 64];

  const int tid  = threadIdx.x;
  const int lane = tid & 63;
  const int w    = tid >> 6;   // 0..7
  const int wm   = w >> 2;     // 0..1
  const int wn   = w & 3;      // 0..3
  const int m0   = blockIdx.y * 128;
  const int n0   = blockIdx.x * 128;

  const int sr  = tid >> 3;    // A-stage row (0..63, +64 second half)
  const int sc  = tid & 7;     // A-stage chunk
  const int brl = lane >> 3;   // B-stage row within 8-row group
  const int bch = lane & 7;    // B-stage chunk

  f32x4 acc[4][2];
#pragma unroll
  for (int i = 0; i < 4; ++i)
#pragma unroll
    for (int j = 0; j < 2; ++j) acc[i][j] = (f32x4)0.0f;

  const int nT = kdim >> 6;

  auto stage = [&](int t, int buf) {
    const int kt = t << 6;
    // A: 128 rows x 64 bf16; fp32 load + convert + swizzled ds_write_b128
#pragma unroll
    for (int half = 0; half < 2; ++half) {
      const int row = sr + half * 64;
      const float* ag = A + (size_t)(m0 + row) * ldA + kt + sc * 8;
      float4 f0 = *(const float4*)ag;
      float4 f1 = *(const float4*)(ag + 4);
      ushort8 u;
      u[0]=f2b(f0.x); u[1]=f2b(f0.y); u[2]=f2b(f0.z); u[3]=f2b(f0.w);
      u[4]=f2b(f1.x); u[5]=f2b(f1.y); u[6]=f2b(f1.z); u[7]=f2b(f1.w);
      *(ushort8*)(&As[buf][row * 64 + ((sc ^ (row & 7)) * 8)]) = u;
    }
    // B: 128 rows x 64 bf16; global_load_lds, linear LDS dest + pre-swizzled source
#pragma unroll
    for (int jr = 0; jr < 2; ++jr) {
      const int rbase = jr * 64 + w * 8;       // wave-uniform
      const int grow  = rbase + brl;
      const unsigned short* src =
          B + (size_t)(n0 + grow) * ldB + kt + ((bch ^ brl) * 8);
      gload_lds16(src, &Bs[buf][rbase * 64]);
    }
  };

  auto frag = [&](const unsigned short* S, int row, int chunk) -> short8 {
    return *(const short8*)(S + row * 64 + ((chunk ^ (row & 7)) * 8));
  };

  stage(0, 0);
  __syncthreads();
  int buf = 0;
  for (int t = 0; t < nT; ++t) {
    if (t + 1 < nT) stage(t + 1, buf ^ 1);
    const unsigned short* Ab = As[buf];
    const unsigned short* Bb = Bs[buf];
#pragma unroll
    for (int kk = 0; kk < 2; ++kk) {
      const int ck = kk * 4 + (lane >> 4);
      short8 a[4], b[2];
#pragma unroll
      for (int mi = 0; mi < 4; ++mi)
        a[mi] = frag(Ab, wm * 64 + mi * 16 + (lane & 15), ck);
#pragma unroll
      for (int ni = 0; ni < 2; ++ni)
        b[ni] = frag(Bb, wn * 32 + ni * 16 + (lane & 15), ck);
#pragma unroll
      for (int mi = 0; mi < 4; ++mi)
#pragma unroll
        for (int ni = 0; ni < 2; ++ni)
          acc[mi][ni] = __builtin_amdgcn_mfma_f32_16x16x32_bf16(
              a[mi], b[ni], acc[mi][ni], 0, 0, 0);
    }
    __syncthreads();
    buf ^= 1;
  }

  // epilogue: C/D layout col=lane&15, row=(lane>>4)*4+reg
  const int rg = lane >> 4;
  const int cl = lane & 15;
#pragma unroll
  for (int mi = 0; mi < 4; ++mi) {
#pragma unroll
    for (int r = 0; r < 4; ++r) {
      const int row = m0 + wm * 64 + mi * 16 + rg * 4 + r;
      float bv = 0.0f;
      if (HASBIAS) bv = bias[row];
#pragma unroll
      for (int ni = 0; ni < 2; ++ni) {
        const int col = n0 + wn * 32 + ni * 16 + cl;
        const float v = acc[mi][ni][r] + bv;
        if (OUT_BF16)
          ((unsigned short*)Cout)[(size_t)row * ldC + col] = f2b(v);
        else
          ((float*)Cout)[(size_t)row * ldC + col] = v;
      }
    }
  }
}

extern "C" void kernel_launch(void* const* d_in, const int* in_sizes, int n_in,
                              void* d_out, int out_size, void* d_ws, size_t ws_size,
                              hipStream_t stream) {
  const float* x = (const float*)d_in[0];   // [V][K][D] = [V][KD]
  const float* G = (const float*)d_in[1];   // [E][V]
  const float* W = (const float*)d_in[2];   // [O][D][K][C]
  const float* b = (const float*)d_in[3];   // [O][C][D]

  char* ws = (char*)d_ws;
  unsigned short* xb = (unsigned short*)ws;                          // 8 MB bf16 x
  float* Wt          = (float*)(ws + (8u << 20));                    // 1 MB fp32 Wt[j][kd]
  float* bs          = (float*)(ws + (9u << 20));                    // 2 KB bsum[j]
  unsigned short* Zt = (unsigned short*)(ws + (9u << 20) + (1u << 16)); // 8 MB bf16 Zt[j][v]

  hipLaunchKernelGGL(convert_x, dim3(2048), dim3(256), 0, stream, x, xb);
  hipLaunchKernelGGL(repack_w, dim3(1024), dim3(256), 0, stream, W, b, Wt, bs);

  // GEMM1: Zt[j][v] = sum_kd Wt[j][kd] * xb[v][kd] + bsum[j]
  // M=512 (grid.y=4), N=8192 (grid.x=64), K=512
  hipLaunchKernelGGL((gemm_bt<true, true>), dim3(64, 4), dim3(512), 0, stream,
                     Wt, xb, bs, (void*)Zt, KD, KD, V_DIM, KD);

  // GEMM2: out[e][j] = sum_v G[e][v] * Zt[j][v]
  // M=8192 (grid.y=64), N=512 (grid.x=4), K=8192
  hipLaunchKernelGGL((gemm_bt<false, false>), dim3(4, 64), dim3(512), 0, stream,
                     G, Zt, (const float*)nullptr, (void*)d_out,
                     V_DIM, V_DIM, CO, V_DIM);
}

// Round 5
// 502.934 us; speedup vs baseline: 1.0989x; 1.0989x over previous
//
#include <hip/hip_runtime.h>
#include <hip/hip_bf16.h>

// Dims
#define V_DIM 8192
#define E_DIM 8192
#define KD    512   // K*D = 64*8
#define CO    512   // C*O = 64*8

typedef __attribute__((ext_vector_type(8))) short short8;
typedef __attribute__((ext_vector_type(8))) unsigned short ushort8;
typedef __attribute__((ext_vector_type(4))) float f32x4;

__device__ __forceinline__ unsigned short f2b(float f) {
  __hip_bfloat16 h = __float2bfloat16(f);
  return __builtin_bit_cast(unsigned short, h);
}

__device__ __forceinline__ void gload_lds16(const void* g, void* l) {
  __builtin_amdgcn_global_load_lds(
      (const __attribute__((address_space(1))) void*)g,
      (__attribute__((address_space(3))) void*)l, 16, 0, 0);
}

// x (fp32, [V][KD]) -> xb (bf16 bits, same layout)
__global__ void convert_x(const float* __restrict__ x, unsigned short* __restrict__ xb) {
  const size_t i = ((size_t)blockIdx.x * 256 + threadIdx.x) * 8;
  float4 f0 = *(const float4*)(x + i);
  float4 f1 = *(const float4*)(x + i + 4);
  ushort8 u;
  u[0]=f2b(f0.x); u[1]=f2b(f0.y); u[2]=f2b(f0.z); u[3]=f2b(f0.w);
  u[4]=f2b(f1.x); u[5]=f2b(f1.y); u[6]=f2b(f1.z); u[7]=f2b(f1.w);
  *(ushort8*)(xb + i) = u;
}

// Wt[j=c*8+o][kd=k*8+d] = W[o,d,k,c]  (fp32, 512x512); bsum[j] = sum_d b[o,c,d]
__global__ void repack_w(const float* __restrict__ W, const float* __restrict__ b,
                         float* __restrict__ Wt, float* __restrict__ bsum) {
  const int idx = blockIdx.x * 256 + threadIdx.x;  // 0..262143
  const int j = idx >> 9, kd = idx & 511;
  const int c = j >> 3, o = j & 7, k = kd >> 3, d = kd & 7;
  Wt[idx] = W[(((o * 8 + d) * 64 + k) << 6) + c];
  if (idx < 512) {
    const int cc = idx >> 3, oo = idx & 7;
    float s = 0.f;
#pragma unroll
    for (int dd = 0; dd < 8; ++dd) s += b[((oo * 64 + cc) << 3) + dd];
    bsum[idx] = s;
  }
}

// C[m][n] = sum_k A[m][k] * B[n][k]; A fp32 (reg-staged + converted), B bf16.
// 128x128 tile, BK=64, 512 threads (8 waves, 2Mx4N). 3 LDS slots, prefetch
// depth 2, counted vmcnt (never 0 in main loop), raw barriers. LDS 16B-chunk
// XOR swizzle (chunk ^= row&7) on both write and read (B: pre-swizzled global
// source + linear global_load_lds dest).
template<int NT, bool OUT_BF16, bool HASBIAS, bool SWIZ>
__global__ __launch_bounds__(512, 2)
void gemm_bt(const float* __restrict__ A, const unsigned short* __restrict__ B,
             const float* __restrict__ bias, void* __restrict__ Cout,
             int ldA, int ldB, int ldC) {
  static_assert((NT - 2) % 6 == 0, "pipeline needs (NT-2) divisible by 6");
  __shared__ __align__(16) unsigned short As[3][128 * 64];
  __shared__ __align__(16) unsigned short Bs[3][128 * 64];

  const int tid  = threadIdx.x;
  const int lane = tid & 63;
  const int w    = tid >> 6;   // 0..7
  const int wm   = w >> 2;     // 0..1
  const int wn   = w & 3;      // 0..3

  int bm, bn;
  if (SWIZ) {
    // gridDim == (4, 64); group the 4 n-sharers of an m-panel on one XCD.
    int bid = blockIdx.x + (blockIdx.y << 2);
    bid = ((bid & 7) << 5) | (bid >> 3);   // bijective: 256 % 8 == 0
    bm = bid >> 2; bn = bid & 3;
  } else {
    bm = blockIdx.y; bn = blockIdx.x;
  }
  const int m0 = bm * 128, n0 = bn * 128;

  const int sr  = tid >> 3;   // A-stage row (0..63; +64 second half)
  const int sc  = tid & 7;    // A-stage 16B chunk
  const int brl = lane >> 3;  // B-stage row-in-group
  const int bch = lane & 7;   // B-stage chunk

  const float* agB0 = A + (size_t)(m0 + sr) * ldA + sc * 8;
  const float* agB1 = agB0 + (size_t)64 * ldA;
  const int aw0 = sr * 64 + ((sc ^ (sr & 7)) * 8);  // (sr+64)&7 == sr&7
  const int aw1 = aw0 + 64 * 64;

  const unsigned short* bsrc0 =
      B + (size_t)(n0 + w * 8 + brl) * ldB + ((bch ^ brl) * 8);
  const unsigned short* bsrc1 = bsrc0 + (size_t)64 * ldB;
  const int bd0 = (w * 8) * 64;
  const int bd1 = (64 + w * 8) * 64;

  f32x4 acc[4][2];
#pragma unroll
  for (int i = 0; i < 4; ++i)
#pragma unroll
    for (int j = 0; j < 2; ++j) acc[i][j] = (f32x4)0.0f;

  f32x4 pf[2][4];

#define STAGE_LOAD(T, C, SLOT) do {                                       \
    const int kt_ = (T) << 6;                                             \
    pf[(C)][0] = *(const f32x4*)(agB0 + kt_);                             \
    pf[(C)][1] = *(const f32x4*)(agB0 + kt_ + 4);                         \
    pf[(C)][2] = *(const f32x4*)(agB1 + kt_);                             \
    pf[(C)][3] = *(const f32x4*)(agB1 + kt_ + 4);                         \
    gload_lds16(bsrc0 + kt_, &Bs[(SLOT)][bd0]);                           \
    gload_lds16(bsrc1 + kt_, &Bs[(SLOT)][bd1]);                           \
  } while (0)

#define STAGE_WRITE(C, SLOT) do {                                         \
    ushort8 u0_, u1_;                                                     \
    u0_[0]=f2b(pf[(C)][0][0]); u0_[1]=f2b(pf[(C)][0][1]);                 \
    u0_[2]=f2b(pf[(C)][0][2]); u0_[3]=f2b(pf[(C)][0][3]);                 \
    u0_[4]=f2b(pf[(C)][1][0]); u0_[5]=f2b(pf[(C)][1][1]);                 \
    u0_[6]=f2b(pf[(C)][1][2]); u0_[7]=f2b(pf[(C)][1][3]);                 \
    u1_[0]=f2b(pf[(C)][2][0]); u1_[1]=f2b(pf[(C)][2][1]);                 \
    u1_[2]=f2b(pf[(C)][2][2]); u1_[3]=f2b(pf[(C)][2][3]);                 \
    u1_[4]=f2b(pf[(C)][3][0]); u1_[5]=f2b(pf[(C)][3][1]);                 \
    u1_[6]=f2b(pf[(C)][3][2]); u1_[7]=f2b(pf[(C)][3][3]);                 \
    *(ushort8*)(&As[(SLOT)][aw0]) = u0_;                                  \
    *(ushort8*)(&As[(SLOT)][aw1]) = u1_;                                  \
  } while (0)

#define COMPUTE(SLOT) do {                                                \
    const unsigned short* Ab_ = As[(SLOT)];                               \
    const unsigned short* Bb_ = Bs[(SLOT)];                               \
    _Pragma("unroll")                                                     \
    for (int kk = 0; kk < 2; ++kk) {                                      \
      const int ck_ = kk * 4 + (lane >> 4);                               \
      short8 af_[4], bf_[2];                                              \
      _Pragma("unroll")                                                   \
      for (int mi = 0; mi < 4; ++mi) {                                    \
        const int r_ = wm * 64 + mi * 16 + (lane & 15);                   \
        af_[mi] = *(const short8*)(Ab_ + r_ * 64 + ((ck_ ^ (r_ & 7)) * 8)); \
      }                                                                   \
      _Pragma("unroll")                                                   \
      for (int ni = 0; ni < 2; ++ni) {                                    \
        const int r_ = wn * 32 + ni * 16 + (lane & 15);                   \
        bf_[ni] = *(const short8*)(Bb_ + r_ * 64 + ((ck_ ^ (r_ & 7)) * 8)); \
      }                                                                   \
      _Pragma("unroll")                                                   \
      for (int mi = 0; mi < 4; ++mi)                                      \
        _Pragma("unroll")                                                 \
        for (int ni = 0; ni < 2; ++ni)                                    \
          acc[mi][ni] = __builtin_amdgcn_mfma_f32_16x16x32_bf16(          \
              af_[mi], bf_[ni], acc[mi][ni], 0, 0, 0);                    \
    }                                                                     \
  } while (0)

  // Prologue: fill stages 0,1; write A(0) into slot 0.
  STAGE_LOAD(0, 0, 0);
  STAGE_LOAD(1, 1, 1);
  STAGE_WRITE(0, 0);

#pragma unroll 1
  for (int tb = 0; tb < NT - 2; tb += 6) {
#pragma unroll
    for (int jj = 0; jj < 6; ++jj) {
      STAGE_LOAD(tb + jj + 2, jj & 1, (jj + 2) % 3);
      asm volatile("s_waitcnt vmcnt(6)" ::: "memory");   // stage t+1 landed
      STAGE_WRITE((jj + 1) & 1, (jj + 1) % 3);
      asm volatile("s_waitcnt lgkmcnt(0)" ::: "memory"); // own ds_writes visible
      __builtin_amdgcn_sched_barrier(0);
      __builtin_amdgcn_s_barrier();
      __builtin_amdgcn_sched_barrier(0);
      COMPUTE(jj % 3);
      __builtin_amdgcn_sched_barrier(0);
      __builtin_amdgcn_s_barrier();
    }
  }

  // Tail: t = NT-2 (write last A, drain all), then consume last two slots.
  asm volatile("s_waitcnt vmcnt(0)" ::: "memory");
  STAGE_WRITE((NT - 1) & 1, (NT - 1) % 3);
  asm volatile("s_waitcnt lgkmcnt(0)" ::: "memory");
  __builtin_amdgcn_sched_barrier(0);
  __builtin_amdgcn_s_barrier();
  __builtin_amdgcn_sched_barrier(0);
  COMPUTE((NT - 2) % 3);
  __builtin_amdgcn_sched_barrier(0);
  __builtin_amdgcn_s_barrier();
  COMPUTE((NT - 1) % 3);

#undef STAGE_LOAD
#undef STAGE_WRITE
#undef COMPUTE

  // Epilogue: C/D layout col=lane&15, row=(lane>>4)*4+reg
  const int rg = lane >> 4;
  const int cl = lane & 15;
#pragma unroll
  for (int mi = 0; mi < 4; ++mi) {
#pragma unroll
    for (int r = 0; r < 4; ++r) {
      const int row = m0 + wm * 64 + mi * 16 + rg * 4 + r;
      float bv = 0.0f;
      if (HASBIAS) bv = bias[row];
#pragma unroll
      for (int ni = 0; ni < 2; ++ni) {
        const int col = n0 + wn * 32 + ni * 16 + cl;
        const float v = acc[mi][ni][r] + bv;
        if (OUT_BF16)
          ((unsigned short*)Cout)[(size_t)row * ldC + col] = f2b(v);
        else
          ((float*)Cout)[(size_t)row * ldC + col] = v;
      }
    }
  }
}

extern "C" void kernel_launch(void* const* d_in, const int* in_sizes, int n_in,
                              void* d_out, int out_size, void* d_ws, size_t ws_size,
                              hipStream_t stream) {
  const float* x = (const float*)d_in[0];   // [V][KD]
  const float* G = (const float*)d_in[1];   // [E][V]
  const float* W = (const float*)d_in[2];   // [O][D][K][C]
  const float* b = (const float*)d_in[3];   // [O][C][D]

  char* ws = (char*)d_ws;
  unsigned short* xb = (unsigned short*)ws;                              // 8 MB
  float* Wt          = (float*)(ws + (8u << 20));                        // 1 MB
  float* bs          = (float*)(ws + (9u << 20));                        // 2 KB
  unsigned short* Zt = (unsigned short*)(ws + (9u << 20) + (1u << 16));  // 8 MB

  hipLaunchKernelGGL(convert_x, dim3(2048), dim3(256), 0, stream, x, xb);
  hipLaunchKernelGGL(repack_w, dim3(1024), dim3(256), 0, stream, W, b, Wt, bs);

  // GEMM1: Zt[j][v] = sum_kd Wt[j][kd] * xb[v][kd] + bsum[j]
  // M=512 (grid.y=4), N=8192 (grid.x=64), K=512 -> NT=8
  hipLaunchKernelGGL((gemm_bt<8, true, true, false>), dim3(64, 4), dim3(512), 0,
                     stream, Wt, xb, bs, (void*)Zt, KD, KD, V_DIM);

  // GEMM2: out[e][j] = sum_v G[e][v] * Zt[j][v]
  // M=8192 (grid.y=64), N=512 (grid.x=4), K=8192 -> NT=128
  hipLaunchKernelGGL((gemm_bt<128, false, false, true>), dim3(4, 64), dim3(512), 0,
                     stream, G, Zt, (const float*)nullptr, (void*)d_out,
                     V_DIM, V_DIM, CO);
}

// Round 7
// 474.743 us; speedup vs baseline: 1.1641x; 1.0594x over previous
//
#include <hip/hip_runtime.h>
#include <hip/hip_bf16.h>

// Dims
#define V_DIM 8192
#define E_DIM 8192
#define KD    512   // K*D = 64*8
#define CO    512   // C*O = 64*8

typedef __attribute__((ext_vector_type(8))) short short8;
typedef __attribute__((ext_vector_type(8))) unsigned short ushort8;
typedef __attribute__((ext_vector_type(4))) float f32x4;

__device__ __forceinline__ unsigned short f2b(float f) {
  __hip_bfloat16 h = __float2bfloat16(f);
  return __builtin_bit_cast(unsigned short, h);
}

__device__ __forceinline__ void gload_lds16(const void* g, void* l) {
  __builtin_amdgcn_global_load_lds(
      (const __attribute__((address_space(1))) void*)g,
      (__attribute__((address_space(3))) void*)l, 16, 0, 0);
}

// x (fp32, [V][KD]) -> xb (bf16 bits, same layout)
__global__ void convert_x(const float* __restrict__ x, unsigned short* __restrict__ xb) {
  const size_t i = ((size_t)blockIdx.x * 256 + threadIdx.x) * 8;
  float4 f0 = *(const float4*)(x + i);
  float4 f1 = *(const float4*)(x + i + 4);
  ushort8 u;
  u[0]=f2b(f0.x); u[1]=f2b(f0.y); u[2]=f2b(f0.z); u[3]=f2b(f0.w);
  u[4]=f2b(f1.x); u[5]=f2b(f1.y); u[6]=f2b(f1.z); u[7]=f2b(f1.w);
  *(ushort8*)(xb + i) = u;
}

// Wt[j=c*8+o][kd=k*8+d] = W[o,d,k,c]  (fp32, 512x512); bsum[j] = sum_d b[o,c,d]
__global__ void repack_w(const float* __restrict__ W, const float* __restrict__ b,
                         float* __restrict__ Wt, float* __restrict__ bsum) {
  const int idx = blockIdx.x * 256 + threadIdx.x;  // 0..262143
  const int j = idx >> 9, kd = idx & 511;
  const int c = j >> 3, o = j & 7, k = kd >> 3, d = kd & 7;
  Wt[idx] = W[(((o * 8 + d) * 64 + k) << 6) + c];
  if (idx < 512) {
    const int cc = idx >> 3, oo = idx & 7;
    float s = 0.f;
#pragma unroll
    for (int dd = 0; dd < 8; ++dd) s += b[((oo * 64 + cc) << 3) + dd];
    bsum[idx] = s;
  }
}

// C[m][n] = sum_k A[m][k] * B[n][k]; A fp32 (reg-staged + converted), B bf16.
// 128x128 tile, BK=64, 512 threads (8 waves, 2Mx4N). Phase-overlapped pipeline:
//   phase1: issue STAGE_LOAD(t+2) then COMPUTE(t)  (globals fly under compute)
//   phase2: vmcnt(6) [stage t+1 landed], cvt+ds_write A(t+1), lgkmcnt(0), barrier
// A: 2 LDS slots, B: 3 LDS slots (80 KB total -> 2 blocks/CU). XOR 16B-chunk
// swizzle (chunk ^= row&7) both sides; B via pre-swizzled global source +
// linear global_load_lds dest.
template<int NT, bool OUT_BF16, bool HASBIAS, bool SWIZ>
__global__ __launch_bounds__(512, 2)
void gemm_bt(const float* __restrict__ A, const unsigned short* __restrict__ B,
             const float* __restrict__ bias, void* __restrict__ Cout,
             int ldA, int ldB, int ldC) {
  static_assert((NT - 2) % 6 == 0, "pipeline needs (NT-2) divisible by 6");
  __shared__ __align__(16) unsigned short As[2][128 * 64];
  __shared__ __align__(16) unsigned short Bs[3][128 * 64];

  const int tid  = threadIdx.x;
  const int lane = tid & 63;
  const int w    = tid >> 6;   // 0..7
  const int wm   = w >> 2;     // 0..1
  const int wn   = w & 3;      // 0..3

  int bm, bn;
  if (SWIZ) {
    // gridDim == (4, 64); group the 4 n-sharers of an m-panel on one XCD.
    int bid = blockIdx.x + (blockIdx.y << 2);
    bid = ((bid & 7) << 5) | (bid >> 3);   // bijective: 256 % 8 == 0
    bm = bid >> 2; bn = bid & 3;
  } else {
    bm = blockIdx.y; bn = blockIdx.x;
  }
  const int m0 = bm * 128, n0 = bn * 128;

  const int sr  = tid >> 3;   // A-stage row (0..63; +64 second half)
  const int sc  = tid & 7;    // A-stage 16B chunk
  const int brl = lane >> 3;  // B-stage row-in-group
  const int bch = lane & 7;   // B-stage chunk

  const float* agB0 = A + (size_t)(m0 + sr) * ldA + sc * 8;
  const float* agB1 = agB0 + (size_t)64 * ldA;
  const int aw0 = sr * 64 + ((sc ^ (sr & 7)) * 8);  // (sr+64)&7 == sr&7
  const int aw1 = aw0 + 64 * 64;

  const unsigned short* bsrc0 =
      B + (size_t)(n0 + w * 8 + brl) * ldB + ((bch ^ brl) * 8);
  const unsigned short* bsrc1 = bsrc0 + (size_t)64 * ldB;
  const int bd0 = (w * 8) * 64;
  const int bd1 = (64 + w * 8) * 64;

  f32x4 acc[4][2];
#pragma unroll
  for (int i = 0; i < 4; ++i)
#pragma unroll
    for (int j = 0; j < 2; ++j) acc[i][j] = (f32x4)0.0f;

  f32x4 pf[2][4];

#define STAGE_LOAD(T, C, BSLOT) do {                                      \
    const int kt_ = (T) << 6;                                             \
    pf[(C)][0] = *(const f32x4*)(agB0 + kt_);                             \
    pf[(C)][1] = *(const f32x4*)(agB0 + kt_ + 4);                         \
    pf[(C)][2] = *(const f32x4*)(agB1 + kt_);                             \
    pf[(C)][3] = *(const f32x4*)(agB1 + kt_ + 4);                         \
    gload_lds16(bsrc0 + kt_, &Bs[(BSLOT)][bd0]);                          \
    gload_lds16(bsrc1 + kt_, &Bs[(BSLOT)][bd1]);                          \
  } while (0)

#define STAGE_WRITE(C, ASLOT) do {                                        \
    ushort8 u0_, u1_;                                                     \
    u0_[0]=f2b(pf[(C)][0][0]); u0_[1]=f2b(pf[(C)][0][1]);                 \
    u0_[2]=f2b(pf[(C)][0][2]); u0_[3]=f2b(pf[(C)][0][3]);                 \
    u0_[4]=f2b(pf[(C)][1][0]); u0_[5]=f2b(pf[(C)][1][1]);                 \
    u0_[6]=f2b(pf[(C)][1][2]); u0_[7]=f2b(pf[(C)][1][3]);                 \
    u1_[0]=f2b(pf[(C)][2][0]); u1_[1]=f2b(pf[(C)][2][1]);                 \
    u1_[2]=f2b(pf[(C)][2][2]); u1_[3]=f2b(pf[(C)][2][3]);                 \
    u1_[4]=f2b(pf[(C)][3][0]); u1_[5]=f2b(pf[(C)][3][1]);                 \
    u1_[6]=f2b(pf[(C)][3][2]); u1_[7]=f2b(pf[(C)][3][3]);                 \
    *(ushort8*)(&As[(ASLOT)][aw0]) = u0_;                                 \
    *(ushort8*)(&As[(ASLOT)][aw1]) = u1_;                                 \
  } while (0)

#define COMPUTE(ASLOT, BSLOT) do {                                        \
    const unsigned short* Ab_ = As[(ASLOT)];                              \
    const unsigned short* Bb_ = Bs[(BSLOT)];                              \
    _Pragma("unroll")                                                     \
    for (int kk = 0; kk < 2; ++kk) {                                      \
      const int ck_ = kk * 4 + (lane >> 4);                               \
      short8 af_[4], bf_[2];                                              \
      _Pragma("unroll")                                                   \
      for (int mi = 0; mi < 4; ++mi) {                                    \
        const int r_ = wm * 64 + mi * 16 + (lane & 15);                   \
        af_[mi] = *(const short8*)(Ab_ + r_ * 64 + ((ck_ ^ (r_ & 7)) * 8)); \
      }                                                                   \
      _Pragma("unroll")                                                   \
      for (int ni = 0; ni < 2; ++ni) {                                    \
        const int r_ = wn * 32 + ni * 16 + (lane & 15);                   \
        bf_[ni] = *(const short8*)(Bb_ + r_ * 64 + ((ck_ ^ (r_ & 7)) * 8)); \
      }                                                                   \
      _Pragma("unroll")                                                   \
      for (int mi = 0; mi < 4; ++mi)                                      \
        _Pragma("unroll")                                                 \
        for (int ni = 0; ni < 2; ++ni)                                    \
          acc[mi][ni] = __builtin_amdgcn_mfma_f32_16x16x32_bf16(          \
              af_[mi], bf_[ni], acc[mi][ni], 0, 0, 0);                    \
    }                                                                     \
  } while (0)

#define BAR() do {                                                        \
    __builtin_amdgcn_sched_barrier(0);                                    \
    __builtin_amdgcn_s_barrier();                                         \
    __builtin_amdgcn_sched_barrier(0);                                    \
  } while (0)

  // Prologue: stages 0,1 in flight; A(0) written; everyone synced.
  STAGE_LOAD(0, 0, 0);
  STAGE_LOAD(1, 1, 1);
  asm volatile("s_waitcnt vmcnt(6)" ::: "memory");   // stage 0 landed
  STAGE_WRITE(0, 0);
  asm volatile("s_waitcnt lgkmcnt(0)" ::: "memory");
  BAR();

#pragma unroll 1
  for (int tb = 0; tb < NT - 2; tb += 6) {
#pragma unroll
    for (int jj = 0; jj < 6; ++jj) {
      // phase 1: issue next-next stage, compute current (globals fly under MFMA)
      STAGE_LOAD(tb + jj + 2, jj & 1, (jj + 2) % 3);
      COMPUTE(jj & 1, jj % 3);
      BAR();
      // phase 2 (short): stage t+1 landed; convert+write A(t+1)
      asm volatile("s_waitcnt vmcnt(6)" ::: "memory");
      STAGE_WRITE((jj + 1) & 1, (jj + 1) & 1);
      asm volatile("s_waitcnt lgkmcnt(0)" ::: "memory");
      BAR();
    }
  }

  // Tail: compute NT-2, write A(NT-1) (full drain), compute NT-1.
  COMPUTE((NT - 2) & 1, (NT - 2) % 3);
  BAR();
  asm volatile("s_waitcnt vmcnt(0)" ::: "memory");
  STAGE_WRITE((NT - 1) & 1, (NT - 1) & 1);
  asm volatile("s_waitcnt lgkmcnt(0)" ::: "memory");
  BAR();
  COMPUTE((NT - 1) & 1, (NT - 1) % 3);

#undef STAGE_LOAD
#undef STAGE_WRITE
#undef COMPUTE
#undef BAR

  // Epilogue: C/D layout col=lane&15, row=(lane>>4)*4+reg
  const int rg = lane >> 4;
  const int cl = lane & 15;
#pragma unroll
  for (int mi = 0; mi < 4; ++mi) {
#pragma unroll
    for (int r = 0; r < 4; ++r) {
      const int row = m0 + wm * 64 + mi * 16 + rg * 4 + r;
      float bv = 0.0f;
      if (HASBIAS) bv = bias[row];
#pragma unroll
      for (int ni = 0; ni < 2; ++ni) {
        const int col = n0 + wn * 32 + ni * 16 + cl;
        const float v = acc[mi][ni][r] + bv;
        if (OUT_BF16)
          ((unsigned short*)Cout)[(size_t)row * ldC + col] = f2b(v);
        else
          ((float*)Cout)[(size_t)row * ldC + col] = v;
      }
    }
  }
}

extern "C" void kernel_launch(void* const* d_in, const int* in_sizes, int n_in,
                              void* d_out, int out_size, void* d_ws, size_t ws_size,
                              hipStream_t stream) {
  const float* x = (const float*)d_in[0];   // [V][KD]
  const float* G = (const float*)d_in[1];   // [E][V]
  const float* W = (const float*)d_in[2];   // [O][D][K][C]
  const float* b = (const float*)d_in[3];   // [O][C][D]

  char* ws = (char*)d_ws;
  unsigned short* xb = (unsigned short*)ws;                              // 8 MB
  float* Wt          = (float*)(ws + (8u << 20));                        // 1 MB
  float* bs          = (float*)(ws + (9u << 20));                        // 2 KB
  unsigned short* Zt = (unsigned short*)(ws + (9u << 20) + (1u << 16));  // 8 MB

  hipLaunchKernelGGL(convert_x, dim3(2048), dim3(256), 0, stream, x, xb);
  hipLaunchKernelGGL(repack_w, dim3(1024), dim3(256), 0, stream, W, b, Wt, bs);

  // GEMM1: Zt[j][v] = sum_kd Wt[j][kd] * xb[v][kd] + bsum[j]
  // M=512 (grid.y=4), N=8192 (grid.x=64), K=512 -> NT=8
  hipLaunchKernelGGL((gemm_bt<8, true, true, false>), dim3(64, 4), dim3(512), 0,
                     stream, Wt, xb, bs, (void*)Zt, KD, KD, V_DIM);

  // GEMM2: out[e][j] = sum_v G[e][v] * Zt[j][v]
  // M=8192 (grid.y=64), N=512 (grid.x=4), K=8192 -> NT=128
  hipLaunchKernelGGL((gemm_bt<128, false, false, true>), dim3(4, 64), dim3(512), 0,
                     stream, G, Zt, (const float*)nullptr, (void*)d_out,
                     V_DIM, V_DIM, CO);
}

// Round 10
// 471.296 us; speedup vs baseline: 1.1727x; 1.0073x over previous
//
#include <hip/hip_runtime.h>
#include <hip/hip_bf16.h>

// Dims
#define V_DIM 8192
#define E_DIM 8192
#define KD    512   // K*D = 64*8
#define CO    512   // C*O = 64*8

typedef __attribute__((ext_vector_type(8))) short short8;
typedef __attribute__((ext_vector_type(8))) unsigned short ushort8;
typedef __attribute__((ext_vector_type(4))) float f32x4;

__device__ __forceinline__ unsigned short f2b(float f) {
  __hip_bfloat16 h = __float2bfloat16(f);
  return __builtin_bit_cast(unsigned short, h);
}

__device__ __forceinline__ void gload_lds16(const void* g, void* l) {
  __builtin_amdgcn_global_load_lds(
      (const __attribute__((address_space(1))) void*)g,
      (__attribute__((address_space(3))) void*)l, 16, 0, 0);
}

// x (fp32, [V][KD]) -> xb (bf16 bits, same layout)
__global__ void convert_x(const float* __restrict__ x, unsigned short* __restrict__ xb) {
  const size_t i = ((size_t)blockIdx.x * 256 + threadIdx.x) * 8;
  float4 f0 = *(const float4*)(x + i);
  float4 f1 = *(const float4*)(x + i + 4);
  ushort8 u;
  u[0]=f2b(f0.x); u[1]=f2b(f0.y); u[2]=f2b(f0.z); u[3]=f2b(f0.w);
  u[4]=f2b(f1.x); u[5]=f2b(f1.y); u[6]=f2b(f1.z); u[7]=f2b(f1.w);
  *(ushort8*)(xb + i) = u;
}

// Wt[j=c*8+o][kd=k*8+d] = W[o,d,k,c]  (fp32, 512x512); bsum[j] = sum_d b[o,c,d]
__global__ void repack_w(const float* __restrict__ W, const float* __restrict__ b,
                         float* __restrict__ Wt, float* __restrict__ bsum) {
  const int idx = blockIdx.x * 256 + threadIdx.x;  // 0..262143
  const int j = idx >> 9, kd = idx & 511;
  const int c = j >> 3, o = j & 7, k = kd >> 3, d = kd & 7;
  Wt[idx] = W[(((o * 8 + d) * 64 + k) << 6) + c];
  if (idx < 512) {
    const int cc = idx >> 3, oo = idx & 7;
    float s = 0.f;
#pragma unroll
    for (int dd = 0; dd < 8; ++dd) s += b[((oo * 64 + cc) << 3) + dd];
    bsum[idx] = s;
  }
}

// d_out zero-fill (harness poisons 0xAA before every timed call)
__global__ void zero_out(float4* __restrict__ p) {
  p[(size_t)blockIdx.x * 256 + threadIdx.x] = make_float4(0.f, 0.f, 0.f, 0.f);
}

// C[m][n] = sum_k A[m][k] * B[n][k]; A fp32 (reg-staged + converted), B bf16.
// 128x128 tile, BK=64, 512 threads (8 waves, 2Mx4N). Phase-overlapped pipeline:
//   phase1: issue STAGE_LOAD(t+2), setprio(1) COMPUTE(t) setprio(0)
//   phase2: vmcnt(6) [stage t+1 landed], cvt+ds_write A(t+1), lgkmcnt(0), barrier
// A: 2 LDS slots, B: 3 LDS slots (80 KB -> 2 blocks/CU with split-K grid).
// Split-K: blockIdx.z selects a K-slice of NT tiles; ATOMIC epilogue adds
// partials into pre-zeroed fp32 C.
template<int NT, bool OUT_BF16, bool HASBIAS, bool SWIZ, bool ATOMIC>
__global__ __launch_bounds__(512, 2)
void gemm_bt(const float* __restrict__ A, const unsigned short* __restrict__ B,
             const float* __restrict__ bias, void* __restrict__ Cout,
             int ldA, int ldB, int ldC) {
  __shared__ __align__(16) unsigned short As[2][128 * 64];
  __shared__ __align__(16) unsigned short Bs[3][128 * 64];

  const int tid  = threadIdx.x;
  const int lane = tid & 63;
  const int w    = tid >> 6;   // 0..7
  const int wm   = w >> 2;     // 0..1
  const int wn   = w & 3;      // 0..3

  int bm, bn;
  if (SWIZ) {
    // per-z-slice grid is (4, 64); group the 4 n-sharers of an m-panel on one XCD.
    int bid = blockIdx.x + (blockIdx.y << 2);
    bid = ((bid & 7) << 5) | (bid >> 3);   // bijective: 256 % 8 == 0
    bm = bid >> 2; bn = bid & 3;
  } else {
    bm = blockIdx.y; bn = blockIdx.x;
  }
  const int m0 = bm * 128, n0 = bn * 128;
  const int koff = blockIdx.z * (NT << 6);   // split-K element offset

  const int sr  = tid >> 3;   // A-stage row (0..63; +64 second half)
  const int sc  = tid & 7;    // A-stage 16B chunk
  const int brl = lane >> 3;  // B-stage row-in-group
  const int bch = lane & 7;   // B-stage chunk

  const float* agB0 = A + (size_t)(m0 + sr) * ldA + koff + sc * 8;
  const float* agB1 = agB0 + (size_t)64 * ldA;
  const int aw0 = sr * 64 + ((sc ^ (sr & 7)) * 8);  // (sr+64)&7 == sr&7
  const int aw1 = aw0 + 64 * 64;

  const unsigned short* bsrc0 =
      B + (size_t)(n0 + w * 8 + brl) * ldB + koff + ((bch ^ brl) * 8);
  const unsigned short* bsrc1 = bsrc0 + (size_t)64 * ldB;
  const int bd0 = (w * 8) * 64;
  const int bd1 = (64 + w * 8) * 64;

  f32x4 acc[4][2];
#pragma unroll
  for (int i = 0; i < 4; ++i)
#pragma unroll
    for (int j = 0; j < 2; ++j) acc[i][j] = (f32x4)0.0f;

  f32x4 pf[2][4];

#define STAGE_LOAD(T, C, BSLOT) do {                                      \
    const int kt_ = (T) << 6;                                             \
    pf[(C)][0] = *(const f32x4*)(agB0 + kt_);                             \
    pf[(C)][1] = *(const f32x4*)(agB0 + kt_ + 4);                         \
    pf[(C)][2] = *(const f32x4*)(agB1 + kt_);                             \
    pf[(C)][3] = *(const f32x4*)(agB1 + kt_ + 4);                         \
    gload_lds16(bsrc0 + kt_, &Bs[(BSLOT)][bd0]);                          \
    gload_lds16(bsrc1 + kt_, &Bs[(BSLOT)][bd1]);                          \
  } while (0)

#define STAGE_WRITE(C, ASLOT) do {                                        \
    ushort8 u0_, u1_;                                                     \
    u0_[0]=f2b(pf[(C)][0][0]); u0_[1]=f2b(pf[(C)][0][1]);                 \
    u0_[2]=f2b(pf[(C)][0][2]); u0_[3]=f2b(pf[(C)][0][3]);                 \
    u0_[4]=f2b(pf[(C)][1][0]); u0_[5]=f2b(pf[(C)][1][1]);                 \
    u0_[6]=f2b(pf[(C)][1][2]); u0_[7]=f2b(pf[(C)][1][3]);                 \
    u1_[0]=f2b(pf[(C)][2][0]); u1_[1]=f2b(pf[(C)][2][1]);                 \
    u1_[2]=f2b(pf[(C)][2][2]); u1_[3]=f2b(pf[(C)][2][3]);                 \
    u1_[4]=f2b(pf[(C)][3][0]); u1_[5]=f2b(pf[(C)][3][1]);                 \
    u1_[6]=f2b(pf[(C)][3][2]); u1_[7]=f2b(pf[(C)][3][3]);                 \
    *(ushort8*)(&As[(ASLOT)][aw0]) = u0_;                                 \
    *(ushort8*)(&As[(ASLOT)][aw1]) = u1_;                                 \
  } while (0)

#define COMPUTE(ASLOT, BSLOT) do {                                        \
    const unsigned short* Ab_ = As[(ASLOT)];                              \
    const unsigned short* Bb_ = Bs[(BSLOT)];                              \
    _Pragma("unroll")                                                     \
    for (int kk = 0; kk < 2; ++kk) {                                      \
      const int ck_ = kk * 4 + (lane >> 4);                               \
      short8 af_[4], bf_[2];                                              \
      _Pragma("unroll")                                                   \
      for (int mi = 0; mi < 4; ++mi) {                                    \
        const int r_ = wm * 64 + mi * 16 + (lane & 15);                   \
        af_[mi] = *(const short8*)(Ab_ + r_ * 64 + ((ck_ ^ (r_ & 7)) * 8)); \
      }                                                                   \
      _Pragma("unroll")                                                   \
      for (int ni = 0; ni < 2; ++ni) {                                    \
        const int r_ = wn * 32 + ni * 16 + (lane & 15);                   \
        bf_[ni] = *(const short8*)(Bb_ + r_ * 64 + ((ck_ ^ (r_ & 7)) * 8)); \
      }                                                                   \
      _Pragma("unroll")                                                   \
      for (int mi = 0; mi < 4; ++mi)                                      \
        _Pragma("unroll")                                                 \
        for (int ni = 0; ni < 2; ++ni)                                    \
          acc[mi][ni] = __builtin_amdgcn_mfma_f32_16x16x32_bf16(          \
              af_[mi], bf_[ni], acc[mi][ni], 0, 0, 0);                    \
    }                                                                     \
  } while (0)

#define BAR() do {                                                        \
    __builtin_amdgcn_sched_barrier(0);                                    \
    __builtin_amdgcn_s_barrier();                                         \
    __builtin_amdgcn_sched_barrier(0);                                    \
  } while (0)

#define STEP(T, PA, PA1, PB2) do {                                        \
    STAGE_LOAD((T) + 2, PA, PB2);                                         \
    __builtin_amdgcn_s_setprio(1);                                        \
    COMPUTE(PA, (T) % 3);                                                 \
    __builtin_amdgcn_s_setprio(0);                                        \
    BAR();                                                                \
    asm volatile("s_waitcnt vmcnt(6)" ::: "memory");                      \
    STAGE_WRITE(PA1, PA1);                                                \
    asm volatile("s_waitcnt lgkmcnt(0)" ::: "memory");                    \
    BAR();                                                                \
  } while (0)

  // Prologue: stages 0,1 in flight; A(0) written; everyone synced.
  STAGE_LOAD(0, 0, 0);
  STAGE_LOAD(1, 1, 1);
  asm volatile("s_waitcnt vmcnt(6)" ::: "memory");   // stage 0 landed
  STAGE_WRITE(0, 0);
  asm volatile("s_waitcnt lgkmcnt(0)" ::: "memory");
  BAR();

  constexpr int NIT  = NT - 2;          // iterations t = 0 .. NT-3
  constexpr int MAIN = (NIT / 6) * 6;   // multiple of 6 (pf/slot period)

#pragma unroll 1
  for (int tb = 0; tb < MAIN; tb += 6) {
#pragma unroll
    for (int jj = 0; jj < 6; ++jj)
      STEP(tb + jj, jj & 1, (jj + 1) & 1, (jj + 2) % 3);
  }
  // constexpr remainder (fully unrolled; MAIN even, indices fold to constants)
#pragma unroll
  for (int jj = 0; jj < NIT - MAIN; ++jj)
    STEP(MAIN + jj, (MAIN + jj) & 1, (MAIN + jj + 1) & 1, (MAIN + jj + 2) % 3);

  // Tail: compute NT-2, write A(NT-1) (full drain), compute NT-1.
  __builtin_amdgcn_s_setprio(1);
  COMPUTE((NT - 2) & 1, (NT - 2) % 3);
  __builtin_amdgcn_s_setprio(0);
  BAR();
  asm volatile("s_waitcnt vmcnt(0)" ::: "memory");
  STAGE_WRITE((NT - 1) & 1, (NT - 1) & 1);
  asm volatile("s_waitcnt lgkmcnt(0)" ::: "memory");
  BAR();
  COMPUTE((NT - 1) & 1, (NT - 1) % 3);

#undef STAGE_LOAD
#undef STAGE_WRITE
#undef COMPUTE
#undef BAR
#undef STEP

  // Epilogue: C/D layout col=lane&15, row=(lane>>4)*4+reg
  const int rg = lane >> 4;
  const int cl = lane & 15;
#pragma unroll
  for (int mi = 0; mi < 4; ++mi) {
#pragma unroll
    for (int r = 0; r < 4; ++r) {
      const int row = m0 + wm * 64 + mi * 16 + rg * 4 + r;
      float bv = 0.0f;
      if (HASBIAS) bv = bias[row];
#pragma unroll
      for (int ni = 0; ni < 2; ++ni) {
        const int col = n0 + wn * 32 + ni * 16 + cl;
        const float v = acc[mi][ni][r] + bv;
        if (OUT_BF16) {
          ((unsigned short*)Cout)[(size_t)row * ldC + col] = f2b(v);
        } else if (ATOMIC) {
          atomicAdd(((float*)Cout) + (size_t)row * ldC + col, v);
        } else {
          ((float*)Cout)[(size_t)row * ldC + col] = v;
        }
      }
    }
  }
}

extern "C" void kernel_launch(void* const* d_in, const int* in_sizes, int n_in,
                              void* d_out, int out_size, void* d_ws, size_t ws_size,
                              hipStream_t stream) {
  const float* x = (const float*)d_in[0];   // [V][KD]
  const float* G = (const float*)d_in[1];   // [E][V]
  const float* W = (const float*)d_in[2];   // [O][D][K][C]
  const float* b = (const float*)d_in[3];   // [O][C][D]

  char* ws = (char*)d_ws;
  unsigned short* xb = (unsigned short*)ws;                              // 8 MB
  float* Wt          = (float*)(ws + (8u << 20));                        // 1 MB
  float* bs          = (float*)(ws + (9u << 20));                        // 2 KB
  unsigned short* Zt = (unsigned short*)(ws + (9u << 20) + (1u << 16));  // 8 MB

  hipLaunchKernelGGL(convert_x, dim3(2048), dim3(256), 0, stream, x, xb);
  hipLaunchKernelGGL(repack_w, dim3(1024), dim3(256), 0, stream, W, b, Wt, bs);

  // GEMM1: Zt[j][v] = sum_kd Wt[j][kd] * xb[v][kd] + bsum[j]
  // M=512 (grid.y=4), N=8192 (grid.x=64), K=512 -> NT=8
  hipLaunchKernelGGL((gemm_bt<8, true, true, false, false>), dim3(64, 4), dim3(512),
                     0, stream, Wt, xb, bs, (void*)Zt, KD, KD, V_DIM);

  // zero C, then split-K GEMM2 accumulates into it
  hipLaunchKernelGGL(zero_out, dim3(4096), dim3(256), 0, stream, (float4*)d_out);

  // GEMM2: out[e][j] = sum_v G[e][v] * Zt[j][v]
  // M=8192 (grid.y=64), N=512 (grid.x=4), split-K x2 (grid.z=2, NT=64 each)
  hipLaunchKernelGGL((gemm_bt<64, false, false, true, true>), dim3(4, 64, 2),
                     dim3(512), 0, stream, G, Zt, (const float*)nullptr,
                     (void*)d_out, V_DIM, V_DIM, CO);
}